// Round 1
// baseline (4398.096 us; speedup 1.0000x reference)
//
#include <hip/hip_runtime.h>
#include <hip/hip_bf16.h>
#include <math.h>

#define N_NODES 100000
#define N_EDGES 1600000
#define NFEAT 512
#define NHID 128
#define NCLASS 40

// ---------------------------------------------------------------------------
// GEMM1: h1[M,128] = features[M,512] @ W1[512,128]   (fp32, vector ALU)
// Tile: BM=64, BN=128(full), BK=16. 256 threads, each computes 8x4 outputs.
// ---------------------------------------------------------------------------
__global__ __launch_bounds__(256) void gemm1_kernel(
    const float* __restrict__ A,   // [M,512]
    const float* __restrict__ B,   // [512,128]
    float* __restrict__ C,         // [M,128]
    int M)
{
    __shared__ float As[16][64];    // transposed A tile: As[k][row]
    __shared__ float Bs[16][128];   // Bs[k][col]

    const int tid = threadIdx.x;
    const int cg = tid & 31;        // col group: 4 cols each
    const int rg = tid >> 5;        // row group: 8 rows each
    const int m0 = blockIdx.x * 64;

    float acc[8][4];
    #pragma unroll
    for (int i = 0; i < 8; i++)
        #pragma unroll
        for (int j = 0; j < 4; j++) acc[i][j] = 0.f;

    for (int k0 = 0; k0 < NFEAT; k0 += 16) {
        // Load A tile: 64 rows x 16 k -> each thread one float4 along k
        {
            int row = tid >> 2;
            int kq = (tid & 3) * 4;
            int gr = m0 + row;
            if (gr >= M) gr = M - 1;   // clamp; invalid rows never stored
            const float4 a4 = *(const float4*)&A[(size_t)gr * NFEAT + k0 + kq];
            As[kq + 0][row] = a4.x;
            As[kq + 1][row] = a4.y;
            As[kq + 2][row] = a4.z;
            As[kq + 3][row] = a4.w;
        }
        // Load B tile: 16 x 128 = 512 float4s, 2 per thread
        #pragma unroll
        for (int i = 0; i < 2; i++) {
            int v = tid + i * 256;
            int row = v >> 5;
            int c4 = (v & 31) * 4;
            *(float4*)&Bs[row][c4] = *(const float4*)&B[(size_t)(k0 + row) * NHID + c4];
        }
        __syncthreads();

        #pragma unroll
        for (int k = 0; k < 16; k++) {
            float4 b4 = *(float4*)&Bs[k][cg * 4];
            float4 a0 = *(float4*)&As[k][rg * 8];
            float4 a1 = *(float4*)&As[k][rg * 8 + 4];
            float a[8] = {a0.x, a0.y, a0.z, a0.w, a1.x, a1.y, a1.z, a1.w};
            #pragma unroll
            for (int i = 0; i < 8; i++) {
                acc[i][0] = fmaf(a[i], b4.x, acc[i][0]);
                acc[i][1] = fmaf(a[i], b4.y, acc[i][1]);
                acc[i][2] = fmaf(a[i], b4.z, acc[i][2]);
                acc[i][3] = fmaf(a[i], b4.w, acc[i][3]);
            }
        }
        __syncthreads();
    }

    #pragma unroll
    for (int i = 0; i < 8; i++) {
        int gr = m0 + rg * 8 + i;
        if (gr < M) {
            float4 o = {acc[i][0], acc[i][1], acc[i][2], acc[i][3]};
            *(float4*)&C[(size_t)gr * NHID + cg * 4] = o;
        }
    }
}

// ---------------------------------------------------------------------------
// Scatter1: agg1[dst] += w * h1[src], 128 feats/edge, 32 lanes x float4.
// 8 edges per 256-thread block.
// ---------------------------------------------------------------------------
__global__ __launch_bounds__(256) void scatter1_kernel(
    const int* __restrict__ src, const int* __restrict__ dst,
    const float* __restrict__ ew,
    const float* __restrict__ h1, float* __restrict__ agg1, int E)
{
    const int tid = threadIdx.x;
    const int lane = tid & 31;
    const int e = blockIdx.x * 8 + (tid >> 5);
    if (e >= E) return;
    const int s = src[e];
    const int d = dst[e];
    const float w = ew[e];
    float4 m = *(const float4*)&h1[(size_t)s * NHID + lane * 4];
    float* ap = &agg1[(size_t)d * NHID + lane * 4];
    unsafeAtomicAdd(ap + 0, w * m.x);
    unsafeAtomicAdd(ap + 1, w * m.y);
    unsafeAtomicAdd(ap + 2, w * m.z);
    unsafeAtomicAdd(ap + 3, w * m.w);
}

// ---------------------------------------------------------------------------
// GEMM2: h2[M,40] = relu(agg1[M,128] + b1) @ W2[128,40]
// Block: 32 rows; x tile + transposed W2 in LDS. 5 outputs/thread.
// ---------------------------------------------------------------------------
__global__ __launch_bounds__(256) void gemm2_kernel(
    const float* __restrict__ agg1, const float* __restrict__ b1,
    const float* __restrict__ W2, float* __restrict__ h2, int M)
{
    __shared__ float xs[32][128];
    __shared__ float Wt[40][132];   // transposed W2, padded vs bank conflicts

    const int tid = threadIdx.x;
    const int m0 = blockIdx.x * 32;

    // Load x tile with fused bias+relu: 1024 float4s, 4 per thread
    #pragma unroll
    for (int i = 0; i < 4; i++) {
        int v = tid + i * 256;
        int row = v >> 5;
        int c4 = (v & 31) * 4;
        float4 a = *(const float4*)&agg1[(size_t)(m0 + row) * NHID + c4];
        float4 bb = *(const float4*)&b1[c4];
        a.x = fmaxf(a.x + bb.x, 0.f);
        a.y = fmaxf(a.y + bb.y, 0.f);
        a.z = fmaxf(a.z + bb.z, 0.f);
        a.w = fmaxf(a.w + bb.w, 0.f);
        *(float4*)&xs[row][c4] = a;
    }
    // Load W2 transposed: 5120 elems, 20 per thread
    #pragma unroll
    for (int i = 0; i < 20; i++) {
        int v = tid + i * 256;
        int k = v / 40;
        int c = v - k * 40;
        Wt[c][k] = W2[v];
    }
    __syncthreads();

    #pragma unroll
    for (int i = 0; i < 5; i++) {
        int o = tid + i * 256;       // 0..1279
        int row = o / 40;
        int col = o - row * 40;
        float s = 0.f;
        #pragma unroll
        for (int k4 = 0; k4 < 32; k4++) {
            float4 x4 = *(float4*)&xs[row][k4 * 4];
            float4 w4 = *(float4*)&Wt[col][k4 * 4];
            s = fmaf(x4.x, w4.x, s);
            s = fmaf(x4.y, w4.y, s);
            s = fmaf(x4.z, w4.z, s);
            s = fmaf(x4.w, w4.w, s);
        }
        h2[(size_t)(m0 + row) * NCLASS + col] = s;
    }
}

// ---------------------------------------------------------------------------
// Scatter2: out[dst] += w * h2[src], 40 feats/edge, 8 lanes x 5 floats.
// 32 edges per 256-thread block.
// ---------------------------------------------------------------------------
__global__ __launch_bounds__(256) void scatter2_kernel(
    const int* __restrict__ src, const int* __restrict__ dst,
    const float* __restrict__ ew,
    const float* __restrict__ h2, float* __restrict__ out, int E)
{
    const int tid = threadIdx.x;
    const int lane = tid & 7;
    const int e = blockIdx.x * 32 + (tid >> 3);
    if (e >= E) return;
    const int s = src[e];
    const int d = dst[e];
    const float w = ew[e];
    const float* hp = &h2[(size_t)s * NCLASS + lane * 5];
    float* op = &out[(size_t)d * NCLASS + lane * 5];
    #pragma unroll
    for (int j = 0; j < 5; j++)
        unsafeAtomicAdd(op + j, w * hp[j]);
}

// ---------------------------------------------------------------------------
// Finalize: out = log_softmax(out + b2) per row of 40. One wave per row.
// ---------------------------------------------------------------------------
__global__ __launch_bounds__(256) void finalize_kernel(
    float* __restrict__ out, const float* __restrict__ b2, int M)
{
    const int row = blockIdx.x * 4 + (threadIdx.x >> 6);
    const int lane = threadIdx.x & 63;
    if (row >= M) return;
    float v = -INFINITY;
    if (lane < NCLASS) v = out[(size_t)row * NCLASS + lane] + b2[lane];
    float mx = v;
    #pragma unroll
    for (int o = 32; o > 0; o >>= 1) mx = fmaxf(mx, __shfl_xor(mx, o, 64));
    float ex = (lane < NCLASS) ? expf(v - mx) : 0.f;
    float sm = ex;
    #pragma unroll
    for (int o = 32; o > 0; o >>= 1) sm += __shfl_xor(sm, o, 64);
    if (lane < NCLASS) out[(size_t)row * NCLASS + lane] = v - mx - logf(sm);
}

extern "C" void kernel_launch(void* const* d_in, const int* in_sizes, int n_in,
                              void* d_out, int out_size, void* d_ws, size_t ws_size,
                              hipStream_t stream) {
    const float* features = (const float*)d_in[0];
    const int* edge_src   = (const int*)d_in[1];
    const int* edge_dst   = (const int*)d_in[2];
    const float* edge_w   = (const float*)d_in[3];
    const float* W1       = (const float*)d_in[4];
    const float* b1       = (const float*)d_in[5];
    const float* W2       = (const float*)d_in[6];
    const float* b2       = (const float*)d_in[7];
    float* out = (float*)d_out;

    float* h1   = (float*)d_ws;                       // N*128 floats (51.2 MB)
    float* agg1 = h1 + (size_t)N_NODES * NHID;        // N*128 floats (51.2 MB)
    float* h2   = h1;                                  // reuse h1 buffer after GEMM2 input is agg1

    // Zero accumulators (harness poisons d_out/d_ws with 0xAA every call)
    hipMemsetAsync(agg1, 0, (size_t)N_NODES * NHID * sizeof(float), stream);
    hipMemsetAsync(out, 0, (size_t)N_NODES * NCLASS * sizeof(float), stream);

    // Layer 1 dense: h1 = features @ W1
    gemm1_kernel<<<(N_NODES + 63) / 64, 256, 0, stream>>>(features, W1, h1, N_NODES);

    // Layer 1 spmm: agg1[dst] += w * h1[src]
    scatter1_kernel<<<(N_EDGES + 7) / 8, 256, 0, stream>>>(edge_src, edge_dst, edge_w, h1, agg1, N_EDGES);

    // Layer 2 dense (fused bias+relu on input): h2 = relu(agg1 + b1) @ W2
    gemm2_kernel<<<(N_NODES + 31) / 32, 256, 0, stream>>>(agg1, b1, W2, h2, N_NODES);

    // Layer 2 spmm: out[dst] += w * h2[src]
    scatter2_kernel<<<(N_EDGES + 31) / 32, 256, 0, stream>>>(edge_src, edge_dst, edge_w, h2, out, N_EDGES);

    // out = log_softmax(out + b2)
    finalize_kernel<<<(N_NODES + 3) / 4, 256, 0, stream>>>(out, b2, N_NODES);
}

// Round 2
// 1041.201 us; speedup vs baseline: 4.2241x; 4.2241x over previous
//
#include <hip/hip_runtime.h>
#include <hip/hip_bf16.h>
#include <math.h>

#define N_NODES 100000
#define N_EDGES 1600000
#define NFEAT 512
#define NHID 128
#define NCLASS 40

// ---------------------------------------------------------------------------
// GEMM1: h1[M,128] = features[M,512] @ W1[512,128]   (fp32, vector ALU)
// Tile: BM=64, BN=128(full), BK=16. 256 threads, each computes 8x4 outputs.
// ---------------------------------------------------------------------------
__global__ __launch_bounds__(256) void gemm1_kernel(
    const float* __restrict__ A,   // [M,512]
    const float* __restrict__ B,   // [512,128]
    float* __restrict__ C,         // [M,128]
    int M)
{
    __shared__ float As[16][64];    // transposed A tile: As[k][row]
    __shared__ float Bs[16][128];   // Bs[k][col]

    const int tid = threadIdx.x;
    const int cg = tid & 31;        // col group: 4 cols each
    const int rg = tid >> 5;        // row group: 8 rows each
    const int m0 = blockIdx.x * 64;

    float acc[8][4];
    #pragma unroll
    for (int i = 0; i < 8; i++)
        #pragma unroll
        for (int j = 0; j < 4; j++) acc[i][j] = 0.f;

    for (int k0 = 0; k0 < NFEAT; k0 += 16) {
        {
            int row = tid >> 2;
            int kq = (tid & 3) * 4;
            int gr = m0 + row;
            if (gr >= M) gr = M - 1;   // clamp; invalid rows never stored
            const float4 a4 = *(const float4*)&A[(size_t)gr * NFEAT + k0 + kq];
            As[kq + 0][row] = a4.x;
            As[kq + 1][row] = a4.y;
            As[kq + 2][row] = a4.z;
            As[kq + 3][row] = a4.w;
        }
        #pragma unroll
        for (int i = 0; i < 2; i++) {
            int v = tid + i * 256;
            int row = v >> 5;
            int c4 = (v & 31) * 4;
            *(float4*)&Bs[row][c4] = *(const float4*)&B[(size_t)(k0 + row) * NHID + c4];
        }
        __syncthreads();

        #pragma unroll
        for (int k = 0; k < 16; k++) {
            float4 b4 = *(float4*)&Bs[k][cg * 4];
            float4 a0 = *(float4*)&As[k][rg * 8];
            float4 a1 = *(float4*)&As[k][rg * 8 + 4];
            float a[8] = {a0.x, a0.y, a0.z, a0.w, a1.x, a1.y, a1.z, a1.w};
            #pragma unroll
            for (int i = 0; i < 8; i++) {
                acc[i][0] = fmaf(a[i], b4.x, acc[i][0]);
                acc[i][1] = fmaf(a[i], b4.y, acc[i][1]);
                acc[i][2] = fmaf(a[i], b4.z, acc[i][2]);
                acc[i][3] = fmaf(a[i], b4.w, acc[i][3]);
            }
        }
        __syncthreads();
    }

    #pragma unroll
    for (int i = 0; i < 8; i++) {
        int gr = m0 + rg * 8 + i;
        if (gr < M) {
            float4 o = {acc[i][0], acc[i][1], acc[i][2], acc[i][3]};
            *(float4*)&C[(size_t)gr * NHID + cg * 4] = o;
        }
    }
}

// ---------------------------------------------------------------------------
// Edge sort by dst: histogram -> single-block scan -> placement scatter
// ---------------------------------------------------------------------------
__global__ __launch_bounds__(256) void hist_kernel(
    const int* __restrict__ dst, int* __restrict__ counts, int E)
{
    int e = blockIdx.x * 256 + threadIdx.x;
    if (e < E) atomicAdd(&counts[dst[e]], 1);
}

__global__ __launch_bounds__(1024) void scan_kernel(
    const int* __restrict__ counts, int* __restrict__ offsets,
    int* __restrict__ cursor, int N)
{
    __shared__ int sh[1024];
    const int t = threadIdx.x;
    const int CH = (N + 1023) / 1024;
    const int beg = t * CH;
    const int end = min(beg + CH, N);
    int sum = 0;
    for (int i = beg; i < end; i++) sum += counts[i];
    sh[t] = sum;
    __syncthreads();
    for (int off = 1; off < 1024; off <<= 1) {
        int v = (t >= off) ? sh[t - off] : 0;
        __syncthreads();
        sh[t] += v;
        __syncthreads();
    }
    int run = sh[t] - sum;   // exclusive prefix
    for (int i = beg; i < end; i++) {
        offsets[i] = run;
        cursor[i] = run;
        run += counts[i];
    }
    if (t == 1023) offsets[N] = sh[1023];
}

__global__ __launch_bounds__(256) void scatter_edges_kernel(
    const int* __restrict__ src, const int* __restrict__ dst,
    const float* __restrict__ w, int* __restrict__ cursor,
    int2* __restrict__ sorted, int E)
{
    int e = blockIdx.x * 256 + threadIdx.x;
    if (e >= E) return;
    int d = dst[e];
    int p = atomicAdd(&cursor[d], 1);
    sorted[p] = make_int2(src[e], __float_as_int(w[e]));
}

// ---------------------------------------------------------------------------
// seg_agg1: x[n] = relu(sum_{e: dst=n} w_e * h1[src_e] + b1). 32 lanes/node.
// ---------------------------------------------------------------------------
__global__ __launch_bounds__(256) void seg_agg1_kernel(
    const int2* __restrict__ sorted, const int* __restrict__ offsets,
    const float* __restrict__ h1, const float* __restrict__ b1,
    float* __restrict__ x, int N)
{
    const int tid = threadIdx.x;
    const int lane = tid & 31;
    const int node = blockIdx.x * 8 + (tid >> 5);
    if (node >= N) return;
    const int beg = offsets[node];
    const int end = offsets[node + 1];
    float4 acc = {0.f, 0.f, 0.f, 0.f};
    for (int c = beg; c < end; c += 32) {
        int m = end - c;
        if (m > 32) m = 32;
        int s = 0, wb = 0;
        if (lane < m) { int2 sw = sorted[c + lane]; s = sw.x; wb = sw.y; }
        for (int j = 0; j < m; j++) {
            int sj = __shfl(s, j, 32);
            float wj = __int_as_float(__shfl(wb, j, 32));
            float4 v = *(const float4*)&h1[(size_t)sj * NHID + lane * 4];
            acc.x = fmaf(wj, v.x, acc.x);
            acc.y = fmaf(wj, v.y, acc.y);
            acc.z = fmaf(wj, v.z, acc.z);
            acc.w = fmaf(wj, v.w, acc.w);
        }
    }
    float4 bb = *(const float4*)&b1[lane * 4];
    acc.x = fmaxf(acc.x + bb.x, 0.f);
    acc.y = fmaxf(acc.y + bb.y, 0.f);
    acc.z = fmaxf(acc.z + bb.z, 0.f);
    acc.w = fmaxf(acc.w + bb.w, 0.f);
    *(float4*)&x[(size_t)node * NHID + lane * 4] = acc;
}

// ---------------------------------------------------------------------------
// GEMM2 (plain): h2[M,40] = x[M,128] @ W2[128,40]
// ---------------------------------------------------------------------------
__global__ __launch_bounds__(256) void gemm2_kernel(
    const float* __restrict__ x, const float* __restrict__ W2,
    float* __restrict__ h2, int M)
{
    __shared__ float xs[32][128];
    __shared__ float Wt[40][132];

    const int tid = threadIdx.x;
    const int m0 = blockIdx.x * 32;

    #pragma unroll
    for (int i = 0; i < 4; i++) {
        int v = tid + i * 256;
        int row = v >> 5;
        int c4 = (v & 31) * 4;
        *(float4*)&xs[row][c4] = *(const float4*)&x[(size_t)(m0 + row) * NHID + c4];
    }
    #pragma unroll
    for (int i = 0; i < 20; i++) {
        int v = tid + i * 256;
        int k = v / 40;
        int c = v - k * 40;
        Wt[c][k] = W2[v];
    }
    __syncthreads();

    #pragma unroll
    for (int i = 0; i < 5; i++) {
        int o = tid + i * 256;
        int row = o / 40;
        int col = o - row * 40;
        float s = 0.f;
        #pragma unroll
        for (int k4 = 0; k4 < 32; k4++) {
            float4 x4 = *(float4*)&xs[row][k4 * 4];
            float4 w4 = *(float4*)&Wt[col][k4 * 4];
            s = fmaf(x4.x, w4.x, s);
            s = fmaf(x4.y, w4.y, s);
            s = fmaf(x4.z, w4.z, s);
            s = fmaf(x4.w, w4.w, s);
        }
        h2[(size_t)(m0 + row) * NCLASS + col] = s;
    }
}

// ---------------------------------------------------------------------------
// seg_agg2 + finalize: out[n] = log_softmax(sum w_e*h2[src_e] + b2).
// 16 lanes/node; lanes 0..9 each own 4 of the 40 classes (float4 aligned:
// row stride 160 B is 16 B-multiple).
// ---------------------------------------------------------------------------
__global__ __launch_bounds__(256) void seg_agg2_kernel(
    const int2* __restrict__ sorted, const int* __restrict__ offsets,
    const float* __restrict__ h2, const float* __restrict__ b2,
    float* __restrict__ out, int N)
{
    const int tid = threadIdx.x;
    const int lane = tid & 15;
    const int node = blockIdx.x * 16 + (tid >> 4);
    if (node >= N) return;
    const int beg = offsets[node];
    const int end = offsets[node + 1];
    float4 acc = {0.f, 0.f, 0.f, 0.f};
    for (int c = beg; c < end; c += 16) {
        int m = end - c;
        if (m > 16) m = 16;
        int s = 0, wb = 0;
        if (lane < m) { int2 sw = sorted[c + lane]; s = sw.x; wb = sw.y; }
        for (int j = 0; j < m; j++) {
            int sj = __shfl(s, j, 16);
            float wj = __int_as_float(__shfl(wb, j, 16));
            if (lane < 10) {
                float4 v = *(const float4*)&h2[(size_t)sj * NCLASS + lane * 4];
                acc.x = fmaf(wj, v.x, acc.x);
                acc.y = fmaf(wj, v.y, acc.y);
                acc.z = fmaf(wj, v.z, acc.z);
                acc.w = fmaf(wj, v.w, acc.w);
            }
        }
    }
    float mx;
    if (lane < 10) {
        float4 bb = *(const float4*)&b2[lane * 4];
        acc.x += bb.x; acc.y += bb.y; acc.z += bb.z; acc.w += bb.w;
        mx = fmaxf(fmaxf(acc.x, acc.y), fmaxf(acc.z, acc.w));
    } else {
        mx = -INFINITY;
    }
    #pragma unroll
    for (int o = 8; o > 0; o >>= 1) mx = fmaxf(mx, __shfl_xor(mx, o, 16));
    float sm = 0.f;
    if (lane < 10)
        sm = expf(acc.x - mx) + expf(acc.y - mx) + expf(acc.z - mx) + expf(acc.w - mx);
    #pragma unroll
    for (int o = 8; o > 0; o >>= 1) sm += __shfl_xor(sm, o, 16);
    if (lane < 10) {
        float l = mx + logf(sm);
        float4 o4 = {acc.x - l, acc.y - l, acc.z - l, acc.w - l};
        *(float4*)&out[(size_t)node * NCLASS + lane * 4] = o4;
    }
}

// ---------------------------------------------------------------------------
// Fallback (atomic) path kernels — used only if ws_size is too small for the
// sort-based path. Identical to round-1 implementation.
// ---------------------------------------------------------------------------
__global__ __launch_bounds__(256) void scatter1_atomic_kernel(
    const int* __restrict__ src, const int* __restrict__ dst,
    const float* __restrict__ ew,
    const float* __restrict__ h1, float* __restrict__ agg1, int E)
{
    const int tid = threadIdx.x;
    const int lane = tid & 31;
    const int e = blockIdx.x * 8 + (tid >> 5);
    if (e >= E) return;
    const int s = src[e];
    const int d = dst[e];
    const float w = ew[e];
    float4 m = *(const float4*)&h1[(size_t)s * NHID + lane * 4];
    float* ap = &agg1[(size_t)d * NHID + lane * 4];
    unsafeAtomicAdd(ap + 0, w * m.x);
    unsafeAtomicAdd(ap + 1, w * m.y);
    unsafeAtomicAdd(ap + 2, w * m.z);
    unsafeAtomicAdd(ap + 3, w * m.w);
}

__global__ __launch_bounds__(256) void relu_bias_kernel(
    float* __restrict__ x, const float* __restrict__ b1, int M)
{
    int v = blockIdx.x * 256 + threadIdx.x;       // one float4 per thread
    int row = v >> 5;
    int c4 = (v & 31) * 4;
    if (row >= M) return;
    float4 a = *(float4*)&x[(size_t)row * NHID + c4];
    float4 bb = *(const float4*)&b1[c4];
    a.x = fmaxf(a.x + bb.x, 0.f);
    a.y = fmaxf(a.y + bb.y, 0.f);
    a.z = fmaxf(a.z + bb.z, 0.f);
    a.w = fmaxf(a.w + bb.w, 0.f);
    *(float4*)&x[(size_t)row * NHID + c4] = a;
}

__global__ __launch_bounds__(256) void scatter2_atomic_kernel(
    const int* __restrict__ src, const int* __restrict__ dst,
    const float* __restrict__ ew,
    const float* __restrict__ h2, float* __restrict__ out, int E)
{
    const int tid = threadIdx.x;
    const int lane = tid & 7;
    const int e = blockIdx.x * 32 + (tid >> 3);
    if (e >= E) return;
    const int s = src[e];
    const int d = dst[e];
    const float w = ew[e];
    const float* hp = &h2[(size_t)s * NCLASS + lane * 5];
    float* op = &out[(size_t)d * NCLASS + lane * 5];
    #pragma unroll
    for (int j = 0; j < 5; j++)
        unsafeAtomicAdd(op + j, w * hp[j]);
}

__global__ __launch_bounds__(256) void finalize_kernel(
    float* __restrict__ out, const float* __restrict__ b2, int M)
{
    const int row = blockIdx.x * 4 + (threadIdx.x >> 6);
    const int lane = threadIdx.x & 63;
    if (row >= M) return;
    float v = -INFINITY;
    if (lane < NCLASS) v = out[(size_t)row * NCLASS + lane] + b2[lane];
    float mx = v;
    #pragma unroll
    for (int o = 32; o > 0; o >>= 1) mx = fmaxf(mx, __shfl_xor(mx, o, 64));
    float ex = (lane < NCLASS) ? expf(v - mx) : 0.f;
    float sm = ex;
    #pragma unroll
    for (int o = 32; o > 0; o >>= 1) sm += __shfl_xor(sm, o, 64);
    if (lane < NCLASS) out[(size_t)row * NCLASS + lane] = v - mx - logf(sm);
}

extern "C" void kernel_launch(void* const* d_in, const int* in_sizes, int n_in,
                              void* d_out, int out_size, void* d_ws, size_t ws_size,
                              hipStream_t stream) {
    const float* features = (const float*)d_in[0];
    const int* edge_src   = (const int*)d_in[1];
    const int* edge_dst   = (const int*)d_in[2];
    const float* edge_w   = (const float*)d_in[3];
    const float* W1       = (const float*)d_in[4];
    const float* b1       = (const float*)d_in[5];
    const float* W2       = (const float*)d_in[6];
    const float* b2       = (const float*)d_in[7];
    float* out = (float*)d_out;

    const size_t NH = (size_t)N_NODES * NHID;        // 12.8M floats
    // Sort-path workspace layout (floats):
    //   h1:      [0, NH)
    //   x:       [NH, 2*NH)
    //   sorted:  [2*NH, 2*NH + 2*E)   (int2 pairs, 8B-aligned: 2*NH is even)
    //   offsets: 100001 ints
    //   cursor:  100000 ints
    //   counts:  100000 ints
    const size_t need = (2 * NH + 2 * (size_t)N_EDGES + (N_NODES + 1) + N_NODES + N_NODES)
                        * sizeof(float);

    if (ws_size >= need) {
        float* h1      = (float*)d_ws;
        float* x       = h1 + NH;
        int2*  sorted  = (int2*)(x + NH);
        int*   offsets = (int*)(sorted + N_EDGES);
        int*   cursor  = offsets + (N_NODES + 1);
        int*   counts  = cursor + N_NODES;
        float* h2      = h1;   // h1 dead after seg_agg1

        hipMemsetAsync(counts, 0, N_NODES * sizeof(int), stream);

        // Edge sort by dst (runs concurrently-ordered with gemm1 on stream)
        hist_kernel<<<(N_EDGES + 255) / 256, 256, 0, stream>>>(edge_dst, counts, N_EDGES);
        scan_kernel<<<1, 1024, 0, stream>>>(counts, offsets, cursor, N_NODES);
        scatter_edges_kernel<<<(N_EDGES + 255) / 256, 256, 0, stream>>>(
            edge_src, edge_dst, edge_w, cursor, sorted, N_EDGES);

        gemm1_kernel<<<(N_NODES + 63) / 64, 256, 0, stream>>>(features, W1, h1, N_NODES);

        seg_agg1_kernel<<<(N_NODES + 7) / 8, 256, 0, stream>>>(
            sorted, offsets, h1, b1, x, N_NODES);

        gemm2_kernel<<<(N_NODES + 31) / 32, 256, 0, stream>>>(x, W2, h2, N_NODES);

        seg_agg2_kernel<<<(N_NODES + 15) / 16, 256, 0, stream>>>(
            sorted, offsets, h2, b2, out, N_NODES);
    } else {
        // Fallback: round-1 atomic path (needs 102.4 MB ws)
        float* h1   = (float*)d_ws;
        float* agg1 = h1 + NH;
        float* h2   = h1;

        hipMemsetAsync(agg1, 0, NH * sizeof(float), stream);
        hipMemsetAsync(out, 0, (size_t)N_NODES * NCLASS * sizeof(float), stream);

        gemm1_kernel<<<(N_NODES + 63) / 64, 256, 0, stream>>>(features, W1, h1, N_NODES);
        scatter1_atomic_kernel<<<(N_EDGES + 7) / 8, 256, 0, stream>>>(
            edge_src, edge_dst, edge_w, h1, agg1, N_EDGES);
        relu_bias_kernel<<<((N_NODES * 32) + 255) / 256, 256, 0, stream>>>(agg1, b1, N_NODES);
        gemm2_kernel<<<(N_NODES + 31) / 32, 256, 0, stream>>>(agg1, W2, h2, N_NODES);
        scatter2_atomic_kernel<<<(N_EDGES + 31) / 32, 256, 0, stream>>>(
            edge_src, edge_dst, edge_w, h2, out, N_EDGES);
        finalize_kernel<<<(N_NODES + 3) / 4, 256, 0, stream>>>(out, b2, N_NODES);
    }
}

// Round 3
// 825.228 us; speedup vs baseline: 5.3296x; 1.2617x over previous
//
#include <hip/hip_runtime.h>
#include <hip/hip_bf16.h>
#include <math.h>

#define N_NODES 100000
#define N_EDGES 1600000
#define NFEAT 512
#define NHID 128
#define NCLASS 40

#define SCAN_TILE 1024
#define SCAN_NB ((N_NODES + SCAN_TILE - 1) / SCAN_TILE)   // 98

// ---------------------------------------------------------------------------
// GEMM1: h1[M,128] = features[M,512] @ W1[512,128]   (fp32, vector ALU)
// ---------------------------------------------------------------------------
__global__ __launch_bounds__(256) void gemm1_kernel(
    const float* __restrict__ A,   // [M,512]
    const float* __restrict__ B,   // [512,128]
    float* __restrict__ C,         // [M,128]
    int M)
{
    __shared__ float As[16][64];    // transposed A tile: As[k][row]
    __shared__ float Bs[16][128];   // Bs[k][col]

    const int tid = threadIdx.x;
    const int cg = tid & 31;        // col group: 4 cols each
    const int rg = tid >> 5;        // row group: 8 rows each
    const int m0 = blockIdx.x * 64;

    float acc[8][4];
    #pragma unroll
    for (int i = 0; i < 8; i++)
        #pragma unroll
        for (int j = 0; j < 4; j++) acc[i][j] = 0.f;

    for (int k0 = 0; k0 < NFEAT; k0 += 16) {
        {
            int row = tid >> 2;
            int kq = (tid & 3) * 4;
            int gr = m0 + row;
            if (gr >= M) gr = M - 1;   // clamp; invalid rows never stored
            const float4 a4 = *(const float4*)&A[(size_t)gr * NFEAT + k0 + kq];
            As[kq + 0][row] = a4.x;
            As[kq + 1][row] = a4.y;
            As[kq + 2][row] = a4.z;
            As[kq + 3][row] = a4.w;
        }
        #pragma unroll
        for (int i = 0; i < 2; i++) {
            int v = tid + i * 256;
            int row = v >> 5;
            int c4 = (v & 31) * 4;
            *(float4*)&Bs[row][c4] = *(const float4*)&B[(size_t)(k0 + row) * NHID + c4];
        }
        __syncthreads();

        #pragma unroll
        for (int k = 0; k < 16; k++) {
            float4 b4 = *(float4*)&Bs[k][cg * 4];
            float4 a0 = *(float4*)&As[k][rg * 8];
            float4 a1 = *(float4*)&As[k][rg * 8 + 4];
            float a[8] = {a0.x, a0.y, a0.z, a0.w, a1.x, a1.y, a1.z, a1.w};
            #pragma unroll
            for (int i = 0; i < 8; i++) {
                acc[i][0] = fmaf(a[i], b4.x, acc[i][0]);
                acc[i][1] = fmaf(a[i], b4.y, acc[i][1]);
                acc[i][2] = fmaf(a[i], b4.z, acc[i][2]);
                acc[i][3] = fmaf(a[i], b4.w, acc[i][3]);
            }
        }
        __syncthreads();
    }

    #pragma unroll
    for (int i = 0; i < 8; i++) {
        int gr = m0 + rg * 8 + i;
        if (gr < M) {
            float4 o = {acc[i][0], acc[i][1], acc[i][2], acc[i][3]};
            *(float4*)&C[(size_t)gr * NHID + cg * 4] = o;
        }
    }
}

// ---------------------------------------------------------------------------
// Edge sort by dst: histogram -> hierarchical scan -> placement scatter
// ---------------------------------------------------------------------------
__global__ __launch_bounds__(256) void hist_kernel(
    const int* __restrict__ dst, int* __restrict__ counts, int E)
{
    int e = blockIdx.x * 256 + threadIdx.x;
    if (e < E) atomicAdd(&counts[dst[e]], 1);
}

// Stage A: per-tile sums. 98 blocks x 256 threads, 4 counts/thread.
__global__ __launch_bounds__(256) void scan_partials_kernel(
    const int* __restrict__ counts, int* __restrict__ partials, int N)
{
    __shared__ int sh[256];
    const int t = threadIdx.x;
    const int base = blockIdx.x * SCAN_TILE + t * 4;
    int s = 0;
    #pragma unroll
    for (int j = 0; j < 4; j++) {
        int i = base + j;
        if (i < N) s += counts[i];
    }
    sh[t] = s;
    __syncthreads();
    #pragma unroll
    for (int off = 128; off > 0; off >>= 1) {
        if (t < off) sh[t] += sh[t + off];
        __syncthreads();
    }
    if (t == 0) partials[blockIdx.x] = sh[0];
}

// Stage B: one small block scans the 98 partials (exclusive), writes offsets[N].
__global__ __launch_bounds__(128) void scan_offsets_kernel(
    const int* __restrict__ partials, int* __restrict__ bofs,
    int* __restrict__ offsets, int N)
{
    __shared__ int sh[128];
    const int t = threadIdx.x;
    int v = (t < SCAN_NB) ? partials[t] : 0;
    sh[t] = v;
    __syncthreads();
    #pragma unroll
    for (int off = 1; off < 128; off <<= 1) {
        int u = (t >= off) ? sh[t - off] : 0;
        __syncthreads();
        sh[t] += u;
        __syncthreads();
    }
    if (t < SCAN_NB) bofs[t] = sh[t] - v;     // exclusive
    if (t == 127) offsets[N] = sh[127];        // total (== N_EDGES)
}

// Stage C: per-tile exclusive scan + tile offset; writes offsets & cursor.
__global__ __launch_bounds__(256) void scan_final_kernel(
    const int* __restrict__ counts, const int* __restrict__ bofs,
    int* __restrict__ offsets, int* __restrict__ cursor, int N)
{
    __shared__ int sh[256];
    const int t = threadIdx.x;
    const int base = blockIdx.x * SCAN_TILE + t * 4;
    int c[4] = {0, 0, 0, 0};
    #pragma unroll
    for (int j = 0; j < 4; j++) {
        int i = base + j;
        if (i < N) c[j] = counts[i];
    }
    int s = c[0] + c[1] + c[2] + c[3];
    sh[t] = s;
    __syncthreads();
    #pragma unroll
    for (int off = 1; off < 256; off <<= 1) {
        int u = (t >= off) ? sh[t - off] : 0;
        __syncthreads();
        sh[t] += u;
        __syncthreads();
    }
    int run = bofs[blockIdx.x] + sh[t] - s;    // exclusive prefix for this thread
    #pragma unroll
    for (int j = 0; j < 4; j++) {
        int i = base + j;
        if (i < N) {
            offsets[i] = run;
            cursor[i] = run;
            run += c[j];
        }
    }
}

__global__ __launch_bounds__(256) void scatter_edges_kernel(
    const int* __restrict__ src, const int* __restrict__ dst,
    const float* __restrict__ w, int* __restrict__ cursor,
    int2* __restrict__ sorted, int E)
{
    int e = blockIdx.x * 256 + threadIdx.x;
    if (e >= E) return;
    int d = dst[e];
    int p = atomicAdd(&cursor[d], 1);
    sorted[p] = make_int2(src[e], __float_as_int(w[e]));
}

// ---------------------------------------------------------------------------
// seg_agg1: x[n] = relu(sum_{e: dst=n} w_e * h1[src_e] + b1). 32 lanes/node.
// ---------------------------------------------------------------------------
__global__ __launch_bounds__(256) void seg_agg1_kernel(
    const int2* __restrict__ sorted, const int* __restrict__ offsets,
    const float* __restrict__ h1, const float* __restrict__ b1,
    float* __restrict__ x, int N)
{
    const int tid = threadIdx.x;
    const int lane = tid & 31;
    const int node = blockIdx.x * 8 + (tid >> 5);
    if (node >= N) return;
    const int beg = offsets[node];
    const int end = offsets[node + 1];
    float4 acc = {0.f, 0.f, 0.f, 0.f};
    for (int c = beg; c < end; c += 32) {
        int m = end - c;
        if (m > 32) m = 32;
        int s = 0, wb = 0;
        if (lane < m) { int2 sw = sorted[c + lane]; s = sw.x; wb = sw.y; }
        for (int j = 0; j < m; j++) {
            int sj = __shfl(s, j, 32);
            float wj = __int_as_float(__shfl(wb, j, 32));
            float4 v = *(const float4*)&h1[(size_t)sj * NHID + lane * 4];
            acc.x = fmaf(wj, v.x, acc.x);
            acc.y = fmaf(wj, v.y, acc.y);
            acc.z = fmaf(wj, v.z, acc.z);
            acc.w = fmaf(wj, v.w, acc.w);
        }
    }
    float4 bb = *(const float4*)&b1[lane * 4];
    acc.x = fmaxf(acc.x + bb.x, 0.f);
    acc.y = fmaxf(acc.y + bb.y, 0.f);
    acc.z = fmaxf(acc.z + bb.z, 0.f);
    acc.w = fmaxf(acc.w + bb.w, 0.f);
    *(float4*)&x[(size_t)node * NHID + lane * 4] = acc;
}

// ---------------------------------------------------------------------------
// GEMM2 (plain): h2[M,40] = x[M,128] @ W2[128,40]
// ---------------------------------------------------------------------------
__global__ __launch_bounds__(256) void gemm2_kernel(
    const float* __restrict__ x, const float* __restrict__ W2,
    float* __restrict__ h2, int M)
{
    __shared__ float xs[32][128];
    __shared__ float Wt[40][132];

    const int tid = threadIdx.x;
    const int m0 = blockIdx.x * 32;

    #pragma unroll
    for (int i = 0; i < 4; i++) {
        int v = tid + i * 256;
        int row = v >> 5;
        int c4 = (v & 31) * 4;
        *(float4*)&xs[row][c4] = *(const float4*)&x[(size_t)(m0 + row) * NHID + c4];
    }
    #pragma unroll
    for (int i = 0; i < 20; i++) {
        int v = tid + i * 256;
        int k = v / 40;
        int c = v - k * 40;
        Wt[c][k] = W2[v];
    }
    __syncthreads();

    #pragma unroll
    for (int i = 0; i < 5; i++) {
        int o = tid + i * 256;
        int row = o / 40;
        int col = o - row * 40;
        float s = 0.f;
        #pragma unroll
        for (int k4 = 0; k4 < 32; k4++) {
            float4 x4 = *(float4*)&xs[row][k4 * 4];
            float4 w4 = *(float4*)&Wt[col][k4 * 4];
            s = fmaf(x4.x, w4.x, s);
            s = fmaf(x4.y, w4.y, s);
            s = fmaf(x4.z, w4.z, s);
            s = fmaf(x4.w, w4.w, s);
        }
        h2[(size_t)(m0 + row) * NCLASS + col] = s;
    }
}

// ---------------------------------------------------------------------------
// seg_agg2 + finalize: out[n] = log_softmax(sum w_e*h2[src_e] + b2).
// ---------------------------------------------------------------------------
__global__ __launch_bounds__(256) void seg_agg2_kernel(
    const int2* __restrict__ sorted, const int* __restrict__ offsets,
    const float* __restrict__ h2, const float* __restrict__ b2,
    float* __restrict__ out, int N)
{
    const int tid = threadIdx.x;
    const int lane = tid & 15;
    const int node = blockIdx.x * 16 + (tid >> 4);
    if (node >= N) return;
    const int beg = offsets[node];
    const int end = offsets[node + 1];
    float4 acc = {0.f, 0.f, 0.f, 0.f};
    for (int c = beg; c < end; c += 16) {
        int m = end - c;
        if (m > 16) m = 16;
        int s = 0, wb = 0;
        if (lane < m) { int2 sw = sorted[c + lane]; s = sw.x; wb = sw.y; }
        for (int j = 0; j < m; j++) {
            int sj = __shfl(s, j, 16);
            float wj = __int_as_float(__shfl(wb, j, 16));
            if (lane < 10) {
                float4 v = *(const float4*)&h2[(size_t)sj * NCLASS + lane * 4];
                acc.x = fmaf(wj, v.x, acc.x);
                acc.y = fmaf(wj, v.y, acc.y);
                acc.z = fmaf(wj, v.z, acc.z);
                acc.w = fmaf(wj, v.w, acc.w);
            }
        }
    }
    float mx;
    if (lane < 10) {
        float4 bb = *(const float4*)&b2[lane * 4];
        acc.x += bb.x; acc.y += bb.y; acc.z += bb.z; acc.w += bb.w;
        mx = fmaxf(fmaxf(acc.x, acc.y), fmaxf(acc.z, acc.w));
    } else {
        mx = -INFINITY;
    }
    #pragma unroll
    for (int o = 8; o > 0; o >>= 1) mx = fmaxf(mx, __shfl_xor(mx, o, 16));
    float sm = 0.f;
    if (lane < 10)
        sm = expf(acc.x - mx) + expf(acc.y - mx) + expf(acc.z - mx) + expf(acc.w - mx);
    #pragma unroll
    for (int o = 8; o > 0; o >>= 1) sm += __shfl_xor(sm, o, 16);
    if (lane < 10) {
        float l = mx + logf(sm);
        float4 o4 = {acc.x - l, acc.y - l, acc.z - l, acc.w - l};
        *(float4*)&out[(size_t)node * NCLASS + lane * 4] = o4;
    }
}

// ---------------------------------------------------------------------------
// Fallback (atomic) path kernels — used only if ws_size is too small.
// ---------------------------------------------------------------------------
__global__ __launch_bounds__(256) void scatter1_atomic_kernel(
    const int* __restrict__ src, const int* __restrict__ dst,
    const float* __restrict__ ew,
    const float* __restrict__ h1, float* __restrict__ agg1, int E)
{
    const int tid = threadIdx.x;
    const int lane = tid & 31;
    const int e = blockIdx.x * 8 + (tid >> 5);
    if (e >= E) return;
    const int s = src[e];
    const int d = dst[e];
    const float w = ew[e];
    float4 m = *(const float4*)&h1[(size_t)s * NHID + lane * 4];
    float* ap = &agg1[(size_t)d * NHID + lane * 4];
    unsafeAtomicAdd(ap + 0, w * m.x);
    unsafeAtomicAdd(ap + 1, w * m.y);
    unsafeAtomicAdd(ap + 2, w * m.z);
    unsafeAtomicAdd(ap + 3, w * m.w);
}

__global__ __launch_bounds__(256) void relu_bias_kernel(
    float* __restrict__ x, const float* __restrict__ b1, int M)
{
    int v = blockIdx.x * 256 + threadIdx.x;
    int row = v >> 5;
    int c4 = (v & 31) * 4;
    if (row >= M) return;
    float4 a = *(float4*)&x[(size_t)row * NHID + c4];
    float4 bb = *(const float4*)&b1[c4];
    a.x = fmaxf(a.x + bb.x, 0.f);
    a.y = fmaxf(a.y + bb.y, 0.f);
    a.z = fmaxf(a.z + bb.z, 0.f);
    a.w = fmaxf(a.w + bb.w, 0.f);
    *(float4*)&x[(size_t)row * NHID + c4] = a;
}

__global__ __launch_bounds__(256) void scatter2_atomic_kernel(
    const int* __restrict__ src, const int* __restrict__ dst,
    const float* __restrict__ ew,
    const float* __restrict__ h2, float* __restrict__ out, int E)
{
    const int tid = threadIdx.x;
    const int lane = tid & 7;
    const int e = blockIdx.x * 32 + (tid >> 3);
    if (e >= E) return;
    const int s = src[e];
    const int d = dst[e];
    const float w = ew[e];
    const float* hp = &h2[(size_t)s * NCLASS + lane * 5];
    float* op = &out[(size_t)d * NCLASS + lane * 5];
    #pragma unroll
    for (int j = 0; j < 5; j++)
        unsafeAtomicAdd(op + j, w * hp[j]);
}

__global__ __launch_bounds__(256) void finalize_kernel(
    float* __restrict__ out, const float* __restrict__ b2, int M)
{
    const int row = blockIdx.x * 4 + (threadIdx.x >> 6);
    const int lane = threadIdx.x & 63;
    if (row >= M) return;
    float v = -INFINITY;
    if (lane < NCLASS) v = out[(size_t)row * NCLASS + lane] + b2[lane];
    float mx = v;
    #pragma unroll
    for (int o = 32; o > 0; o >>= 1) mx = fmaxf(mx, __shfl_xor(mx, o, 64));
    float ex = (lane < NCLASS) ? expf(v - mx) : 0.f;
    float sm = ex;
    #pragma unroll
    for (int o = 32; o > 0; o >>= 1) sm += __shfl_xor(sm, o, 64);
    if (lane < NCLASS) out[(size_t)row * NCLASS + lane] = v - mx - logf(sm);
}

extern "C" void kernel_launch(void* const* d_in, const int* in_sizes, int n_in,
                              void* d_out, int out_size, void* d_ws, size_t ws_size,
                              hipStream_t stream) {
    const float* features = (const float*)d_in[0];
    const int* edge_src   = (const int*)d_in[1];
    const int* edge_dst   = (const int*)d_in[2];
    const float* edge_w   = (const float*)d_in[3];
    const float* W1       = (const float*)d_in[4];
    const float* b1       = (const float*)d_in[5];
    const float* W2       = (const float*)d_in[6];
    const float* b2       = (const float*)d_in[7];
    float* out = (float*)d_out;

    const size_t NH = (size_t)N_NODES * NHID;        // 12.8M floats
    // Sort-path workspace layout (floats):
    //   h1:       [0, NH)
    //   x:        [NH, 2*NH)
    //   sorted:   [2*NH, 2*NH + 2*E)   (int2 pairs; 2*NH is even -> 8B aligned)
    //   offsets:  100001 ints
    //   cursor:   100000 ints
    //   counts:   100000 ints
    //   partials: 98 ints
    //   bofs:     98 ints
    const size_t need = (2 * NH + 2 * (size_t)N_EDGES + (N_NODES + 1) + 2 * (size_t)N_NODES
                         + 2 * SCAN_NB) * sizeof(float);

    if (ws_size >= need) {
        float* h1      = (float*)d_ws;
        float* x       = h1 + NH;
        int2*  sorted  = (int2*)(x + NH);
        int*   offsets = (int*)(sorted + N_EDGES);
        int*   cursor  = offsets + (N_NODES + 1);
        int*   counts  = cursor + N_NODES;
        int*   partials = counts + N_NODES;
        int*   bofs     = partials + SCAN_NB;
        float* h2      = h1;   // h1 dead after seg_agg1

        hipMemsetAsync(counts, 0, N_NODES * sizeof(int), stream);

        // Edge sort by dst
        hist_kernel<<<(N_EDGES + 255) / 256, 256, 0, stream>>>(edge_dst, counts, N_EDGES);
        scan_partials_kernel<<<SCAN_NB, 256, 0, stream>>>(counts, partials, N_NODES);
        scan_offsets_kernel<<<1, 128, 0, stream>>>(partials, bofs, offsets, N_NODES);
        scan_final_kernel<<<SCAN_NB, 256, 0, stream>>>(counts, bofs, offsets, cursor, N_NODES);
        scatter_edges_kernel<<<(N_EDGES + 255) / 256, 256, 0, stream>>>(
            edge_src, edge_dst, edge_w, cursor, sorted, N_EDGES);

        gemm1_kernel<<<(N_NODES + 63) / 64, 256, 0, stream>>>(features, W1, h1, N_NODES);

        seg_agg1_kernel<<<(N_NODES + 7) / 8, 256, 0, stream>>>(
            sorted, offsets, h1, b1, x, N_NODES);

        gemm2_kernel<<<(N_NODES + 31) / 32, 256, 0, stream>>>(x, W2, h2, N_NODES);

        seg_agg2_kernel<<<(N_NODES + 15) / 16, 256, 0, stream>>>(
            sorted, offsets, h2, b2, out, N_NODES);
    } else {
        // Fallback: atomic path (needs 102.4 MB ws)
        float* h1   = (float*)d_ws;
        float* agg1 = h1 + NH;
        float* h2   = h1;

        hipMemsetAsync(agg1, 0, NH * sizeof(float), stream);
        hipMemsetAsync(out, 0, (size_t)N_NODES * NCLASS * sizeof(float), stream);

        gemm1_kernel<<<(N_NODES + 63) / 64, 256, 0, stream>>>(features, W1, h1, N_NODES);
        scatter1_atomic_kernel<<<(N_EDGES + 7) / 8, 256, 0, stream>>>(
            edge_src, edge_dst, edge_w, h1, agg1, N_EDGES);
        relu_bias_kernel<<<((N_NODES * 32) + 255) / 256, 256, 0, stream>>>(agg1, b1, N_NODES);
        gemm2_kernel<<<(N_NODES + 31) / 32, 256, 0, stream>>>(agg1, W2, h2, N_NODES);
        scatter2_atomic_kernel<<<(N_EDGES + 31) / 32, 256, 0, stream>>>(
            edge_src, edge_dst, edge_w, h2, out, N_EDGES);
        finalize_kernel<<<(N_NODES + 3) / 4, 256, 0, stream>>>(out, b2, N_NODES);
    }
}

// Round 4
// 713.274 us; speedup vs baseline: 6.1661x; 1.1570x over previous
//
#include <hip/hip_runtime.h>
#include <hip/hip_bf16.h>
#include <math.h>

#define N_NODES 100000
#define N_EDGES 1600000
#define NFEAT 512
#define NHID 128
#define NCLASS 40

#define SCAN_TILE 1024
#define SCAN_NB ((N_NODES + SCAN_TILE - 1) / SCAN_TILE)   // 98

typedef short bf16x8 __attribute__((ext_vector_type(8)));
typedef float f32x4 __attribute__((ext_vector_type(4)));

static __device__ __forceinline__ unsigned short f32_to_bf16(float f) {
    unsigned int u = __float_as_uint(f);
    unsigned int r = u + 0x7FFFu + ((u >> 16) & 1u);   // RNE
    return (unsigned short)(r >> 16);
}
static __device__ __forceinline__ float bf16_to_f32(unsigned short h) {
    return __uint_as_float(((unsigned int)h) << 16);
}

// ---------------------------------------------------------------------------
// W1 transpose+convert (once per launch): W1[512][128] fp32 -> Wt[128][512] bf16
// ---------------------------------------------------------------------------
__global__ __launch_bounds__(256) void transpose_w1_kernel(
    const float* __restrict__ W1, unsigned short* __restrict__ Wt)
{
    int tid = blockIdx.x * 256 + threadIdx.x;    // 65536 total
    int n = tid >> 9;          // /512
    int k = tid & 511;
    Wt[tid] = f32_to_bf16(W1[k * NHID + n]);
}

// ---------------------------------------------------------------------------
// GEMM1 (bf16 MFMA): h1b[M,128](bf16) = features[M,512](fp32) @ W1
//   - A fragments: load fp32 from global, convert to bf16 in registers
//   - B fragments: 16B loads straight from Wt (L2-resident, 128 KB)
//   - No barriers in K-loop; per-wave LDS staging only for coalesced C-stores
// Block 256 = 4 waves; tile 128 rows (32 rows/wave), full 128 cols.
// ---------------------------------------------------------------------------
__global__ __launch_bounds__(256) void gemm1_mfma_kernel(
    const float* __restrict__ A,            // [M,512]
    const unsigned short* __restrict__ Wt,  // [128][512] bf16, Wt[n][k]
    unsigned short* __restrict__ h1b,       // [M,128] bf16
    int M)
{
    __shared__ unsigned short cstage[4][32 * 130];   // per-wave 32x128 (+2 pad)

    const int tid = threadIdx.x;
    const int w = tid >> 6;
    const int lane = tid & 63;
    const int lr = lane & 15;
    const int quad = lane >> 4;
    const int m0 = blockIdx.x * 128 + w * 32;   // this wave's 32 rows

    f32x4 acc[2][8];
    #pragma unroll
    for (int rt = 0; rt < 2; rt++)
        #pragma unroll
        for (int ct = 0; ct < 8; ct++)
            acc[rt][ct] = (f32x4){0.f, 0.f, 0.f, 0.f};

    int r0 = m0 + lr;
    int r1 = m0 + 16 + lr;
    int r0c = r0 < M ? r0 : M - 1;
    int r1c = r1 < M ? r1 : M - 1;
    const float* a0p = A + (size_t)r0c * NFEAT + quad * 8;
    const float* a1p = A + (size_t)r1c * NFEAT + quad * 8;
    const unsigned short* bp = Wt + (size_t)lr * NFEAT + quad * 8;

    #pragma unroll 2
    for (int k0 = 0; k0 < NFEAT; k0 += 32) {
        float4 a0a = *(const float4*)(a0p + k0);
        float4 a0b = *(const float4*)(a0p + k0 + 4);
        float4 a1a = *(const float4*)(a1p + k0);
        float4 a1b = *(const float4*)(a1p + k0 + 4);

        bf16x8 fb[8];
        #pragma unroll
        for (int ct = 0; ct < 8; ct++)
            fb[ct] = *(const bf16x8*)(bp + (size_t)ct * 16 * NFEAT + k0);

        bf16x8 fa0, fa1;
        fa0[0] = (short)f32_to_bf16(a0a.x); fa0[1] = (short)f32_to_bf16(a0a.y);
        fa0[2] = (short)f32_to_bf16(a0a.z); fa0[3] = (short)f32_to_bf16(a0a.w);
        fa0[4] = (short)f32_to_bf16(a0b.x); fa0[5] = (short)f32_to_bf16(a0b.y);
        fa0[6] = (short)f32_to_bf16(a0b.z); fa0[7] = (short)f32_to_bf16(a0b.w);
        fa1[0] = (short)f32_to_bf16(a1a.x); fa1[1] = (short)f32_to_bf16(a1a.y);
        fa1[2] = (short)f32_to_bf16(a1a.z); fa1[3] = (short)f32_to_bf16(a1a.w);
        fa1[4] = (short)f32_to_bf16(a1b.x); fa1[5] = (short)f32_to_bf16(a1b.y);
        fa1[6] = (short)f32_to_bf16(a1b.z); fa1[7] = (short)f32_to_bf16(a1b.w);

        #pragma unroll
        for (int ct = 0; ct < 8; ct++) {
            acc[0][ct] = __builtin_amdgcn_mfma_f32_16x16x32_bf16(fa0, fb[ct], acc[0][ct], 0, 0, 0);
            acc[1][ct] = __builtin_amdgcn_mfma_f32_16x16x32_bf16(fa1, fb[ct], acc[1][ct], 0, 0, 0);
        }
    }

    // Stage C to LDS (own wave region; no barrier needed), then coalesced store.
    unsigned short* st = cstage[w];
    #pragma unroll
    for (int rt = 0; rt < 2; rt++)
        #pragma unroll
        for (int ct = 0; ct < 8; ct++)
            #pragma unroll
            for (int i = 0; i < 4; i++) {
                int row = rt * 16 + quad * 4 + i;
                int col = ct * 16 + lr;
                st[row * 130 + col] = f32_to_bf16(acc[rt][ct][i]);
            }

    // Readback: inst g covers rows [g*4, g*4+4) -> 1 KB contiguous global store
    #pragma unroll
    for (int g = 0; g < 8; g++) {
        int row = g * 4 + (lane >> 4);          // 0..31
        int c8 = lane & 15;                      // 16B chunk index
        const unsigned short* rp = &st[row * 130 + c8 * 8];
        uint4 v = *(const uint4*)rp;
        int gr = m0 + row;
        if (gr < M)
            *(uint4*)&h1b[(size_t)gr * NHID + c8 * 8] = v;
    }
}

// ---------------------------------------------------------------------------
// Edge sort by dst: histogram -> hierarchical scan -> placement scatter
// ---------------------------------------------------------------------------
__global__ __launch_bounds__(256) void hist_kernel(
    const int* __restrict__ dst, int* __restrict__ counts, int E)
{
    int e = blockIdx.x * 256 + threadIdx.x;
    if (e < E) atomicAdd(&counts[dst[e]], 1);
}

__global__ __launch_bounds__(256) void scan_partials_kernel(
    const int* __restrict__ counts, int* __restrict__ partials, int N)
{
    __shared__ int sh[256];
    const int t = threadIdx.x;
    const int base = blockIdx.x * SCAN_TILE + t * 4;
    int s = 0;
    #pragma unroll
    for (int j = 0; j < 4; j++) {
        int i = base + j;
        if (i < N) s += counts[i];
    }
    sh[t] = s;
    __syncthreads();
    #pragma unroll
    for (int off = 128; off > 0; off >>= 1) {
        if (t < off) sh[t] += sh[t + off];
        __syncthreads();
    }
    if (t == 0) partials[blockIdx.x] = sh[0];
}

__global__ __launch_bounds__(128) void scan_offsets_kernel(
    const int* __restrict__ partials, int* __restrict__ bofs,
    int* __restrict__ offsets, int N)
{
    __shared__ int sh[128];
    const int t = threadIdx.x;
    int v = (t < SCAN_NB) ? partials[t] : 0;
    sh[t] = v;
    __syncthreads();
    #pragma unroll
    for (int off = 1; off < 128; off <<= 1) {
        int u = (t >= off) ? sh[t - off] : 0;
        __syncthreads();
        sh[t] += u;
        __syncthreads();
    }
    if (t < SCAN_NB) bofs[t] = sh[t] - v;
    if (t == 127) offsets[N] = sh[127];
}

__global__ __launch_bounds__(256) void scan_final_kernel(
    const int* __restrict__ counts, const int* __restrict__ bofs,
    int* __restrict__ offsets, int* __restrict__ cursor, int N)
{
    __shared__ int sh[256];
    const int t = threadIdx.x;
    const int base = blockIdx.x * SCAN_TILE + t * 4;
    int c[4] = {0, 0, 0, 0};
    #pragma unroll
    for (int j = 0; j < 4; j++) {
        int i = base + j;
        if (i < N) c[j] = counts[i];
    }
    int s = c[0] + c[1] + c[2] + c[3];
    sh[t] = s;
    __syncthreads();
    #pragma unroll
    for (int off = 1; off < 256; off <<= 1) {
        int u = (t >= off) ? sh[t - off] : 0;
        __syncthreads();
        sh[t] += u;
        __syncthreads();
    }
    int run = bofs[blockIdx.x] + sh[t] - s;
    #pragma unroll
    for (int j = 0; j < 4; j++) {
        int i = base + j;
        if (i < N) {
            offsets[i] = run;
            cursor[i] = run;
            run += c[j];
        }
    }
}

__global__ __launch_bounds__(256) void scatter_edges_kernel(
    const int* __restrict__ src, const int* __restrict__ dst,
    const float* __restrict__ w, int* __restrict__ cursor,
    int2* __restrict__ sorted, int E)
{
    int e = blockIdx.x * 256 + threadIdx.x;
    if (e >= E) return;
    int d = dst[e];
    int p = atomicAdd(&cursor[d], 1);
    sorted[p] = make_int2(src[e], __float_as_int(w[e]));
}

// ---------------------------------------------------------------------------
// seg_agg1 (bf16 gather): x[n] = relu(sum w_e * h1b[src_e] + b1). 32 lanes/node.
// ---------------------------------------------------------------------------
__global__ __launch_bounds__(256) void seg_agg1_kernel(
    const int2* __restrict__ sorted, const int* __restrict__ offsets,
    const unsigned short* __restrict__ h1b, const float* __restrict__ b1,
    float* __restrict__ x, int N)
{
    const int tid = threadIdx.x;
    const int lane = tid & 31;
    const int node = blockIdx.x * 8 + (tid >> 5);
    if (node >= N) return;
    const int beg = offsets[node];
    const int end = offsets[node + 1];
    float4 acc = {0.f, 0.f, 0.f, 0.f};
    for (int c = beg; c < end; c += 32) {
        int m = end - c;
        if (m > 32) m = 32;
        int s = 0, wb = 0;
        if (lane < m) { int2 sw = sorted[c + lane]; s = sw.x; wb = sw.y; }
        for (int j = 0; j < m; j++) {
            int sj = __shfl(s, j, 32);
            float wj = __int_as_float(__shfl(wb, j, 32));
            ushort4 hv = *(const ushort4*)(h1b + (size_t)sj * NHID + lane * 4);
            acc.x = fmaf(wj, bf16_to_f32(hv.x), acc.x);
            acc.y = fmaf(wj, bf16_to_f32(hv.y), acc.y);
            acc.z = fmaf(wj, bf16_to_f32(hv.z), acc.z);
            acc.w = fmaf(wj, bf16_to_f32(hv.w), acc.w);
        }
    }
    float4 bb = *(const float4*)&b1[lane * 4];
    acc.x = fmaxf(acc.x + bb.x, 0.f);
    acc.y = fmaxf(acc.y + bb.y, 0.f);
    acc.z = fmaxf(acc.z + bb.z, 0.f);
    acc.w = fmaxf(acc.w + bb.w, 0.f);
    *(float4*)&x[(size_t)node * NHID + lane * 4] = acc;
}

// ---------------------------------------------------------------------------
// GEMM2 (fp32 vector): h2[M,40] = x[M,128] @ W2[128,40]
// ---------------------------------------------------------------------------
__global__ __launch_bounds__(256) void gemm2_kernel(
    const float* __restrict__ x, const float* __restrict__ W2,
    float* __restrict__ h2, int M)
{
    __shared__ float xs[32][128];
    __shared__ float Wt[40][132];

    const int tid = threadIdx.x;
    const int m0 = blockIdx.x * 32;

    #pragma unroll
    for (int i = 0; i < 4; i++) {
        int v = tid + i * 256;
        int row = v >> 5;
        int c4 = (v & 31) * 4;
        *(float4*)&xs[row][c4] = *(const float4*)&x[(size_t)(m0 + row) * NHID + c4];
    }
    #pragma unroll
    for (int i = 0; i < 20; i++) {
        int v = tid + i * 256;
        int k = v / 40;
        int c = v - k * 40;
        Wt[c][k] = W2[v];
    }
    __syncthreads();

    #pragma unroll
    for (int i = 0; i < 5; i++) {
        int o = tid + i * 256;
        int row = o / 40;
        int col = o - row * 40;
        float s = 0.f;
        #pragma unroll
        for (int k4 = 0; k4 < 32; k4++) {
            float4 x4 = *(float4*)&xs[row][k4 * 4];
            float4 w4 = *(float4*)&Wt[col][k4 * 4];
            s = fmaf(x4.x, w4.x, s);
            s = fmaf(x4.y, w4.y, s);
            s = fmaf(x4.z, w4.z, s);
            s = fmaf(x4.w, w4.w, s);
        }
        h2[(size_t)(m0 + row) * NCLASS + col] = s;
    }
}

// ---------------------------------------------------------------------------
// seg_agg2 + finalize: out[n] = log_softmax(sum w_e*h2[src_e] + b2).
// ---------------------------------------------------------------------------
__global__ __launch_bounds__(256) void seg_agg2_kernel(
    const int2* __restrict__ sorted, const int* __restrict__ offsets,
    const float* __restrict__ h2, const float* __restrict__ b2,
    float* __restrict__ out, int N)
{
    const int tid = threadIdx.x;
    const int lane = tid & 15;
    const int node = blockIdx.x * 16 + (tid >> 4);
    if (node >= N) return;
    const int beg = offsets[node];
    const int end = offsets[node + 1];
    float4 acc = {0.f, 0.f, 0.f, 0.f};
    for (int c = beg; c < end; c += 16) {
        int m = end - c;
        if (m > 16) m = 16;
        int s = 0, wb = 0;
        if (lane < m) { int2 sw = sorted[c + lane]; s = sw.x; wb = sw.y; }
        for (int j = 0; j < m; j++) {
            int sj = __shfl(s, j, 16);
            float wj = __int_as_float(__shfl(wb, j, 16));
            if (lane < 10) {
                float4 v = *(const float4*)&h2[(size_t)sj * NCLASS + lane * 4];
                acc.x = fmaf(wj, v.x, acc.x);
                acc.y = fmaf(wj, v.y, acc.y);
                acc.z = fmaf(wj, v.z, acc.z);
                acc.w = fmaf(wj, v.w, acc.w);
            }
        }
    }
    float mx;
    if (lane < 10) {
        float4 bb = *(const float4*)&b2[lane * 4];
        acc.x += bb.x; acc.y += bb.y; acc.z += bb.z; acc.w += bb.w;
        mx = fmaxf(fmaxf(acc.x, acc.y), fmaxf(acc.z, acc.w));
    } else {
        mx = -INFINITY;
    }
    #pragma unroll
    for (int o = 8; o > 0; o >>= 1) mx = fmaxf(mx, __shfl_xor(mx, o, 16));
    float sm = 0.f;
    if (lane < 10)
        sm = expf(acc.x - mx) + expf(acc.y - mx) + expf(acc.z - mx) + expf(acc.w - mx);
    #pragma unroll
    for (int o = 8; o > 0; o >>= 1) sm += __shfl_xor(sm, o, 16);
    if (lane < 10) {
        float l = mx + logf(sm);
        float4 o4 = {acc.x - l, acc.y - l, acc.z - l, acc.w - l};
        *(float4*)&out[(size_t)node * NCLASS + lane * 4] = o4;
    }
}

extern "C" void kernel_launch(void* const* d_in, const int* in_sizes, int n_in,
                              void* d_out, int out_size, void* d_ws, size_t ws_size,
                              hipStream_t stream) {
    const float* features = (const float*)d_in[0];
    const int* edge_src   = (const int*)d_in[1];
    const int* edge_dst   = (const int*)d_in[2];
    const float* edge_w   = (const float*)d_in[3];
    const float* W1       = (const float*)d_in[4];
    const float* b1       = (const float*)d_in[5];
    const float* W2       = (const float*)d_in[6];
    const float* b2       = (const float*)d_in[7];
    float* out = (float*)d_out;

    const size_t NH = (size_t)N_NODES * NHID;        // 12.8M elems
    // Workspace layout (bytes from base):
    //   x:       fp32 [N,128]            51,200,000
    //   h1b:     bf16 [N,128]            25,600,000   (reused as fp32 h2 [N,40] later)
    //   Wt:      bf16 [128,512]             131,072
    //   sorted:  int2 [E]                12,800,000
    //   offsets: int  [N+1] (pad to 8B)     400,008
    //   cursor:  int  [N]                   400,000
    //   counts:  int  [N]                   400,000
    //   partials/bofs: int [98] each            784
    char* base = (char*)d_ws;
    float*          x       = (float*)base;
    unsigned short* h1b     = (unsigned short*)(base + 51200000);
    unsigned short* Wt      = (unsigned short*)(base + 76800000);
    int2*           sorted  = (int2*)(base + 76931072);
    int*            offsets = (int*)(base + 89731072);
    int*            cursor  = (int*)(base + 90131080);
    int*            counts  = (int*)(base + 90531080);
    int*            partials= (int*)(base + 90931080);
    int*            bofs    = partials + SCAN_NB;
    float*          h2      = (float*)h1b;   // h1b dead after seg_agg1; 16MB < 25.6MB

    hipMemsetAsync(counts, 0, N_NODES * sizeof(int), stream);

    // Edge sort by dst
    hist_kernel<<<(N_EDGES + 255) / 256, 256, 0, stream>>>(edge_dst, counts, N_EDGES);
    scan_partials_kernel<<<SCAN_NB, 256, 0, stream>>>(counts, partials, N_NODES);
    scan_offsets_kernel<<<1, 128, 0, stream>>>(partials, bofs, offsets, N_NODES);
    scan_final_kernel<<<SCAN_NB, 256, 0, stream>>>(counts, bofs, offsets, cursor, N_NODES);
    scatter_edges_kernel<<<(N_EDGES + 255) / 256, 256, 0, stream>>>(
        edge_src, edge_dst, edge_w, cursor, sorted, N_EDGES);

    // Dense layer 1: bf16 MFMA
    transpose_w1_kernel<<<(NFEAT * NHID) / 256, 256, 0, stream>>>(W1, Wt);
    gemm1_mfma_kernel<<<(N_NODES + 127) / 128, 256, 0, stream>>>(features, Wt, h1b, N_NODES);

    // Aggregate 1 (+bias+relu fused)
    seg_agg1_kernel<<<(N_NODES + 7) / 8, 256, 0, stream>>>(
        sorted, offsets, h1b, b1, x, N_NODES);

    // Dense layer 2 (fp32)
    gemm2_kernel<<<(N_NODES + 31) / 32, 256, 0, stream>>>(x, W2, h2, N_NODES);

    // Aggregate 2 + bias + log_softmax fused
    seg_agg2_kernel<<<(N_NODES + 15) / 16, 256, 0, stream>>>(
        sorted, offsets, h2, b2, out, N_NODES);
}